// Round 13
// baseline (265.338 us; speedup 1.0000x reference)
//
#include <hip/hip_runtime.h>

#define NEG 0.2f
#define MAXD 128
#define NR 8
#define GEMM_BLOCKS 1024
#define COUNT_BLOCKS 2048

__device__ __forceinline__ float lrelu(float v) { return v > 0.f ? v : NEG * v; }

// round-to-nearest-even fp32 -> bf16 (returns low 16 bits)
__device__ __forceinline__ unsigned f2bf(float f) {
  unsigned u = __float_as_uint(f);
  u = (u + 0x7FFFu + ((u >> 16) & 1u)) >> 16;
  return u;
}
__device__ __forceinline__ float bf_lo(unsigned u) { return __uint_as_float(u << 16); }
__device__ __forceinline__ float bf_hi(unsigned u) { return __uint_as_float(u & 0xFFFF0000u); }

typedef __attribute__((ext_vector_type(8))) short bf16x8;
typedef __attribute__((ext_vector_type(4))) float f32x4;

// ---- Kernel 0: build Bext (bf16, MFMA-fragment order) from W + att vectors ----
// idx -> (ct, kb, lane, j): value = Wext[k = kb*32+(lane>>4)*8+j][c = ct*16+(lane&15)]
// c in [128,136): ws[k][slot] = sum_j W[k][hd*32+j]*att[hd][j]  (computed ONCE, 1 block)
__global__ __launch_bounds__(256) void k_prep(const float* __restrict__ W,
                                              const float* __restrict__ att_src,
                                              const float* __restrict__ att_dst,
                                              unsigned short* __restrict__ Bext) {
  const int tid = threadIdx.x;
  for (int id = tid; id < 9 * 4 * 64 * 8; id += 256) {
    int j = id & 7, lane = (id >> 3) & 63, kb = (id >> 9) & 3, ct = id >> 11;
    int k = kb * 32 + (lane >> 4) * 8 + j;
    int c = ct * 16 + (lane & 15);
    float v;
    if (c < 128) {
      v = W[k * 128 + c];
    } else {
      int slot = c - 128;
      int hd = slot & 3;
      const float* att = (slot < 4) ? att_src : att_dst;
      float s = 0.f;
      for (int jj = 0; jj < 32; ++jj) s = fmaf(W[k * 128 + hd * 32 + jj], att[hd * 32 + jj], s);
      v = s;
    }
    Bext[id] = (unsigned short)f2bf(v);
  }
}

// ---- Fused kernel (NO LDS): blocks [0,1024) = MFMA GEMM; [1024,3072) = count+rank ----
// B fragments read directly from global Bext (L1/L2-resident, identical per wave).
__global__ __launch_bounds__(256) void k_gemm_count(
    const float* __restrict__ x, const unsigned short* __restrict__ Bext,
    unsigned* __restrict__ hb, float* __restrict__ a_s, float* __restrict__ a_d,
    int N, int ntiles,
    const int* __restrict__ ei, int* __restrict__ cnt, int* __restrict__ rank,
    int E, int rsize)
{
  const int tid = threadIdx.x;
  if (blockIdx.x < GEMM_BLOCKS) {
    // ================= GEMM path =================
    const bf16x8* Bfrag = reinterpret_cast<const bf16x8*>(Bext);
    const int w = tid >> 6, lane = tid & 63;
    const int r16 = lane & 15, g = lane >> 4;
    for (int tile = blockIdx.x; tile < ntiles; tile += GEMM_BLOCKS) {
      int n0 = tile * 64 + w * 16;
      int rowc = min(n0 + r16, N - 1);
      const float* xp = x + (size_t)rowc * 128 + g * 8;
      bf16x8 afr[4];
#pragma unroll
      for (int kb = 0; kb < 4; ++kb) {
        float4 lo = *reinterpret_cast<const float4*>(xp + kb * 32);
        float4 hi = *reinterpret_cast<const float4*>(xp + kb * 32 + 4);
        bf16x8 t;
        t[0] = (short)f2bf(lo.x); t[1] = (short)f2bf(lo.y);
        t[2] = (short)f2bf(lo.z); t[3] = (short)f2bf(lo.w);
        t[4] = (short)f2bf(hi.x); t[5] = (short)f2bf(hi.y);
        t[6] = (short)f2bf(hi.z); t[7] = (short)f2bf(hi.w);
        afr[kb] = t;
      }
#pragma unroll
      for (int ct = 0; ct < 9; ++ct) {
        f32x4 acc = {0.f, 0.f, 0.f, 0.f};
#pragma unroll
        for (int kb = 0; kb < 4; ++kb) {
          bf16x8 bfr = Bfrag[(ct * 4 + kb) * 64 + lane];
          acc = __builtin_amdgcn_mfma_f32_16x16x32_bf16(afr[kb], bfr, acc, 0, 0, 0);
        }
        if (ct < 8) {
#pragma unroll
          for (int r = 0; r < 4; ++r) {
            int orow = n0 + g * 4 + r;
            unsigned b = f2bf(acc[r]);
            unsigned partner = __shfl_xor(b, 1);
            if (((lane & 1) == 0) && orow < N)
              hb[(size_t)orow * 64 + ct * 8 + (r16 >> 1)] = b | (partner << 16);
          }
        } else {
#pragma unroll
          for (int r = 0; r < 4; ++r) {
            int orow = n0 + g * 4 + r;
            if (r16 < 8 && orow < N) {
              if (r16 < 4) a_s[orow * 4 + r16] = acc[r];
              else         a_d[orow * 4 + (r16 - 4)] = acc[r];
            }
          }
        }
      }
    }
  } else {
    // ================= count+rank path (XCD-pinned; 1024%8==0 keeps &7 mapping) =================
    const int r = blockIdx.x & 7;
    const int lo = r * rsize, hi = lo + rsize;
    const int vb = blockIdx.x - GEMM_BLOCKS;
    const int gtid = (vb >> 3) * 256 + tid;
    const int gstride = (COUNT_BLOCKS >> 3) * 256;
    const int nquad = E >> 2;
    const int4* dst4 = reinterpret_cast<const int4*>(ei + E);
    for (int q = gtid; q < nquad; q += gstride) {
      int4 d = dst4[q];
      int e0 = q << 2;
      if (d.x >= lo && d.x < hi) rank[e0]     = atomicAdd(&cnt[d.x], 1);
      if (d.y >= lo && d.y < hi) rank[e0 + 1] = atomicAdd(&cnt[d.y], 1);
      if (d.z >= lo && d.z < hi) rank[e0 + 2] = atomicAdd(&cnt[d.z], 1);
      if (d.w >= lo && d.w < hi) rank[e0 + 3] = atomicAdd(&cnt[d.w], 1);
    }
    for (int e = (nquad << 2) + gtid; e < E; e += gstride) {
      int d = ei[E + e];
      if (d >= lo && d < hi) rank[e] = atomicAdd(&cnt[d], 1);
    }
  }
}

// ---- Scan (3 kernels) ----
__global__ __launch_bounds__(256) void k_scan1(const int* __restrict__ cnt, int* __restrict__ incl,
                                               int* __restrict__ bsum, int N) {
  __shared__ int sm[256];
  int i = blockIdx.x * 256 + threadIdx.x;
  int v = (i < N) ? cnt[i] : 0;
  sm[threadIdx.x] = v;
  __syncthreads();
  for (int off = 1; off < 256; off <<= 1) {
    int t = (threadIdx.x >= off) ? sm[threadIdx.x - off] : 0;
    __syncthreads();
    sm[threadIdx.x] += t;
    __syncthreads();
  }
  if (i < N) incl[i] = sm[threadIdx.x];
  if (threadIdx.x == 255) bsum[blockIdx.x] = sm[255];
}

__global__ __launch_bounds__(512) void k_scan2(int* __restrict__ bsum, int nb) {
  __shared__ int sm[512];
  int v = (threadIdx.x < nb) ? bsum[threadIdx.x] : 0;
  sm[threadIdx.x] = v;
  __syncthreads();
  for (int off = 1; off < 512; off <<= 1) {
    int t = (threadIdx.x >= off) ? sm[threadIdx.x - off] : 0;
    __syncthreads();
    sm[threadIdx.x] += t;
    __syncthreads();
  }
  if (threadIdx.x < nb) bsum[threadIdx.x] = sm[threadIdx.x];
}

__global__ __launch_bounds__(256) void k_scan3(const int* __restrict__ cnt, const int* __restrict__ incl,
                                               const int* __restrict__ bsum, int* __restrict__ offs,
                                               int N, int E) {
  int i = blockIdx.x * 256 + threadIdx.x;
  if (i < N) {
    int base = (blockIdx.x > 0) ? bsum[blockIdx.x - 1] : 0;
    offs[i] = base + incl[i] - cnt[i];
  }
  if (i == 0) offs[N] = E;
}

// ---- XCD-pinned ATOMIC-FREE scatter: ssrc[offs[d]+rank[e]] = src[e] ----
__global__ __launch_bounds__(256) void k_scatter_rank(const int* __restrict__ ei,
                                                      const int* __restrict__ offs,
                                                      const int* __restrict__ rank,
                                                      int* __restrict__ ssrc, int E, int rsize) {
  const int r = blockIdx.x & 7;
  const int lo = r * rsize, hi = lo + rsize;
  const int gtid = (blockIdx.x >> 3) * 256 + threadIdx.x;
  const int gstride = (gridDim.x >> 3) * 256;
  const int nquad = E >> 2;
  const int4* dst4 = reinterpret_cast<const int4*>(ei + E);
  for (int q = gtid; q < nquad; q += gstride) {
    int4 d = dst4[q];
    int e0 = q << 2;
    if (d.x >= lo && d.x < hi) ssrc[offs[d.x] + rank[e0]]     = ei[e0];
    if (d.y >= lo && d.y < hi) ssrc[offs[d.y] + rank[e0 + 1]] = ei[e0 + 1];
    if (d.z >= lo && d.z < hi) ssrc[offs[d.z] + rank[e0 + 2]] = ei[e0 + 2];
    if (d.w >= lo && d.w < hi) ssrc[offs[d.w] + rank[e0 + 3]] = ei[e0 + 3];
  }
  for (int e = (nquad << 2) + gtid; e < E; e += gstride) {
    int d = ei[E + e];
    if (d >= lo && d < hi) ssrc[offs[d] + rank[e]] = ei[e];
  }
}

// ---- k_agg: per-node softmax + aggregation + bias + ELU + fused BN partials ----
// wave per node; lane owns channels (2*lane, 2*lane+1), head = lane>>4
__global__ __launch_bounds__(256) void k_agg(
    const unsigned* __restrict__ hb, const float* __restrict__ a_s, const float* __restrict__ a_d,
    const int* __restrict__ offs, const int* __restrict__ ssrc,
    const float* __restrict__ bias, unsigned* __restrict__ preb,
    float* __restrict__ bnpart, int N)
{
  __shared__ float al[4][MAXD][4];   // per-edge alpha (pre-scaled), per head
  __shared__ int   ls[4][MAXD];      // per-edge src id
  __shared__ float sv[4][128];       // per-wave output row (post-ELU) for BN reduce
  const int wv = threadIdx.x >> 6;
  const int lane = threadIdx.x & 63;
  const int n = blockIdx.x * 4 + wv;

  if (n < N) {
    const int hsel = lane >> 4;
    const int start = offs[n], end = offs[n + 1];
    const int deg = end - start;
    const int jm = deg < MAXD ? deg : MAXD;
    float4 adv = *reinterpret_cast<const float4*>(&a_d[n * 4]);
    float4 asv = *reinterpret_cast<const float4*>(&a_s[n * 4]);
    float e0 = __expf(lrelu(asv.x + adv.x));
    float e1 = __expf(lrelu(asv.y + adv.y));
    float e2 = __expf(lrelu(asv.z + adv.z));
    float e3 = __expf(lrelu(asv.w + adv.w));
    // pass 1: striped exp over all edges; cache first MAXD in LDS
    float p0 = 0.f, p1 = 0.f, p2 = 0.f, p3 = 0.f;
    for (int j = lane; j < deg; j += 64) {
      int s = ssrc[start + j];
      float4 av = *reinterpret_cast<const float4*>(&a_s[s * 4]);
      float x0 = __expf(lrelu(av.x + adv.x));
      float x1 = __expf(lrelu(av.y + adv.y));
      float x2 = __expf(lrelu(av.z + adv.z));
      float x3 = __expf(lrelu(av.w + adv.w));
      p0 += x0; p1 += x1; p2 += x2; p3 += x3;
      if (j < MAXD) {
        float4 t = make_float4(x0, x1, x2, x3);
        *reinterpret_cast<float4*>(&al[wv][j][0]) = t;
        ls[wv][j] = s;
      }
    }
#pragma unroll
    for (int off = 32; off >= 1; off >>= 1) {
      p0 += __shfl_xor(p0, off);
      p1 += __shfl_xor(p1, off);
      p2 += __shfl_xor(p2, off);
      p3 += __shfl_xor(p3, off);
    }
    float rden0 = 1.f / (p0 + e0), rden1 = 1.f / (p1 + e1);
    float rden2 = 1.f / (p2 + e2), rden3 = 1.f / (p3 + e3);
    // pre-scale alphas in LDS
    for (int j = lane; j < jm; j += 64) {
      float4 t = *reinterpret_cast<float4*>(&al[wv][j][0]);
      t.x *= rden0; t.y *= rden1; t.z *= rden2; t.w *= rden3;
      *reinterpret_cast<float4*>(&al[wv][j][0]) = t;
    }
    float ad_c = (hsel < 2) ? (hsel == 0 ? adv.x : adv.y) : (hsel == 2 ? adv.z : adv.w);
    float rden = (hsel < 2) ? (hsel == 0 ? rden0 : rden1) : (hsel == 2 ? rden2 : rden3);
    float esf = (hsel < 2) ? (hsel == 0 ? e0 : e1) : (hsel == 2 ? e2 : e3);
    // pass 2: self + gathers weighted by cached alpha (8 loads in flight)
    unsigned us = hb[(size_t)n * 64 + lane];
    float wself = esf * rden;
    float acc0 = wself * bf_lo(us);
    float acc1 = wself * bf_hi(us);
    int j = 0;
    for (; j + 8 <= jm; j += 8) {
      int4 sA = *reinterpret_cast<int4*>(&ls[wv][j]);
      int4 sB = *reinterpret_cast<int4*>(&ls[wv][j + 4]);
      unsigned u0 = hb[(size_t)sA.x * 64 + lane];
      unsigned u1 = hb[(size_t)sA.y * 64 + lane];
      unsigned u2 = hb[(size_t)sA.z * 64 + lane];
      unsigned u3 = hb[(size_t)sA.w * 64 + lane];
      unsigned u4 = hb[(size_t)sB.x * 64 + lane];
      unsigned u5 = hb[(size_t)sB.y * 64 + lane];
      unsigned u6 = hb[(size_t)sB.z * 64 + lane];
      unsigned u7 = hb[(size_t)sB.w * 64 + lane];
      float w0 = al[wv][j][hsel];
      float w1 = al[wv][j + 1][hsel];
      float w2 = al[wv][j + 2][hsel];
      float w3 = al[wv][j + 3][hsel];
      float w4 = al[wv][j + 4][hsel];
      float w5 = al[wv][j + 5][hsel];
      float w6 = al[wv][j + 6][hsel];
      float w7 = al[wv][j + 7][hsel];
      acc0 = fmaf(w0, bf_lo(u0), acc0);
      acc1 = fmaf(w0, bf_hi(u0), acc1);
      acc0 = fmaf(w1, bf_lo(u1), acc0);
      acc1 = fmaf(w1, bf_hi(u1), acc1);
      acc0 = fmaf(w2, bf_lo(u2), acc0);
      acc1 = fmaf(w2, bf_hi(u2), acc1);
      acc0 = fmaf(w3, bf_lo(u3), acc0);
      acc1 = fmaf(w3, bf_hi(u3), acc1);
      acc0 = fmaf(w4, bf_lo(u4), acc0);
      acc1 = fmaf(w4, bf_hi(u4), acc1);
      acc0 = fmaf(w5, bf_lo(u5), acc0);
      acc1 = fmaf(w5, bf_hi(u5), acc1);
      acc0 = fmaf(w6, bf_lo(u6), acc0);
      acc1 = fmaf(w6, bf_hi(u6), acc1);
      acc0 = fmaf(w7, bf_lo(u7), acc0);
      acc1 = fmaf(w7, bf_hi(u7), acc1);
    }
    for (; j + 4 <= jm; j += 4) {
      int4 s4 = *reinterpret_cast<int4*>(&ls[wv][j]);
      unsigned u0 = hb[(size_t)s4.x * 64 + lane];
      unsigned u1 = hb[(size_t)s4.y * 64 + lane];
      unsigned u2 = hb[(size_t)s4.z * 64 + lane];
      unsigned u3 = hb[(size_t)s4.w * 64 + lane];
      float w0 = al[wv][j][hsel];
      float w1 = al[wv][j + 1][hsel];
      float w2 = al[wv][j + 2][hsel];
      float w3 = al[wv][j + 3][hsel];
      acc0 = fmaf(w0, bf_lo(u0), acc0);
      acc1 = fmaf(w0, bf_hi(u0), acc1);
      acc0 = fmaf(w1, bf_lo(u1), acc0);
      acc1 = fmaf(w1, bf_hi(u1), acc1);
      acc0 = fmaf(w2, bf_lo(u2), acc0);
      acc1 = fmaf(w2, bf_hi(u2), acc1);
      acc0 = fmaf(w3, bf_lo(u3), acc0);
      acc1 = fmaf(w3, bf_hi(u3), acc1);
    }
    for (; j < jm; ++j) {
      int s = ls[wv][j];
      float w = al[wv][j][hsel];
      unsigned u = hb[(size_t)s * 64 + lane];
      acc0 = fmaf(w, bf_lo(u), acc0);
      acc1 = fmaf(w, bf_hi(u), acc1);
    }
    // overflow edges (deg > MAXD): recompute path
    for (int jj = MAXD; jj < deg; ++jj) {
      int s = ssrc[start + jj];
      float q = a_s[s * 4 + hsel];
      unsigned u = hb[(size_t)s * 64 + lane];
      float w = __expf(lrelu(q + ad_c)) * rden;
      acc0 = fmaf(w, bf_lo(u), acc0);
      acc1 = fmaf(w, bf_hi(u), acc1);
    }
    float2 bv = *reinterpret_cast<const float2*>(&bias[2 * lane]);
    float o0 = acc0 + bv.x;
    float o1 = acc1 + bv.y;
    o0 = o0 > 0.f ? o0 : expm1f(o0);
    o1 = o1 > 0.f ? o1 : expm1f(o1);
    preb[(size_t)n * 64 + lane] = f2bf(o0) | (f2bf(o1) << 16);
    sv[wv][2 * lane] = o0;
    sv[wv][2 * lane + 1] = o1;
  } else {
    sv[wv][2 * lane] = 0.f;
    sv[wv][2 * lane + 1] = 0.f;
  }
  __syncthreads();
  // BN partial sums: 128 threads reduce 4 nodes per channel
  int t = threadIdx.x;
  if (t < 128) {
    float s = 0.f, q = 0.f;
#pragma unroll
    for (int w2 = 0; w2 < 4; ++w2) {
      float v = sv[w2][t];
      s += v;
      q = fmaf(v, v, q);
    }
    float* slot = bnpart + (size_t)(blockIdx.x & 63) * 256;
    atomicAdd(&slot[t], s);
    atomicAdd(&slot[128 + t], q);
  }
}

// ---- BN scale/shift from partials ----
__global__ void k_bnfinal(const float* __restrict__ bnpart,
                          const float* __restrict__ gamma, const float* __restrict__ beta,
                          float* __restrict__ sc, float* __restrict__ sh, int N) {
  int c = threadIdx.x;
  float s = 0.f, q = 0.f;
  for (int p = 0; p < 64; ++p) {
    s += bnpart[p * 256 + c];
    q += bnpart[p * 256 + 128 + c];
  }
  float invn = 1.f / (float)N;
  float mean = s * invn;
  float var = q * invn - mean * mean;
  float scl = gamma[c] * rsqrtf(var + 1e-5f);
  sc[c] = scl;
  sh[c] = beta[c] - mean * scl;
}

// ---- apply BN: read packed bf16 pre, write fp32 out ----
__global__ __launch_bounds__(256) void k_bnapply(const unsigned* __restrict__ preb,
                                                 float* __restrict__ out,
                                                 const float* __restrict__ sc,
                                                 const float* __restrict__ sh, int npair2) {
  int i = blockIdx.x * blockDim.x + threadIdx.x;
  if (i >= npair2) return;
  uint2 u = reinterpret_cast<const uint2*>(preb)[i];
  int p0 = i * 2;                 // pair index of first u32
  int c0 = (p0 & 63) * 2;         // channel of low half
  float4 scv = *reinterpret_cast<const float4*>(&sc[c0]);
  float4 shv = *reinterpret_cast<const float4*>(&sh[c0]);
  float4 v;
  v.x = fmaf(bf_lo(u.x), scv.x, shv.x);
  v.y = fmaf(bf_hi(u.x), scv.y, shv.y);
  v.z = fmaf(bf_lo(u.y), scv.z, shv.z);
  v.w = fmaf(bf_hi(u.y), scv.w, shv.w);
  reinterpret_cast<float4*>(out)[i] = v;
}

extern "C" void kernel_launch(void* const* d_in, const int* in_sizes, int n_in,
                              void* d_out, int out_size, void* d_ws, size_t ws_size,
                              hipStream_t stream) {
  const float* x = (const float*)d_in[0];
  const int* ei = (const int*)d_in[1];
  const float* W = (const float*)d_in[2];
  const float* att_src = (const float*)d_in[3];
  const float* att_dst = (const float*)d_in[4];
  const float* bias = (const float*)d_in[5];
  const float* gamma = (const float*)d_in[6];
  const float* beta = (const float*)d_in[7];
  float* out = (float*)d_out;

  const int N = in_sizes[0] / 128;
  const int E = in_sizes[1] / 2;

  char* ws = (char*)d_ws;
  size_t off = 0;
  auto alloc = [&](size_t bytes) {
    void* p = ws + off;
    off = (off + bytes + 255) & ~(size_t)255;
    return p;
  };
  unsigned* hb = (unsigned*)alloc((size_t)N * 64 * 4);  // bf16-packed h
  float* a_s = (float*)alloc((size_t)N * 4 * 4);
  float* a_d = (float*)alloc((size_t)N * 4 * 4);
  int* cnt = (int*)alloc((size_t)N * 4);
  int* incl = (int*)alloc((size_t)N * 4);
  int* offs = (int*)alloc((size_t)(N + 1) * 4);
  int* bsum = (int*)alloc(512 * 4);
  int* rank = (int*)alloc((size_t)E * 4);
  int* ssrc = (int*)alloc((size_t)E * 4);
  unsigned* preb = (unsigned*)alloc((size_t)N * 64 * 4);  // bf16-packed pre
  float* bnpart = (float*)alloc(64 * 256 * 4);
  float* sc = (float*)alloc(128 * 4);
  float* sh = (float*)alloc(128 * 4);
  unsigned short* Bext = (unsigned short*)alloc(9 * 4 * 64 * 8 * 2);  // 36,864 B
  (void)n_in; (void)out_size; (void)ws_size;

  hipMemsetAsync(cnt, 0, (size_t)N * 4, stream);
  hipMemsetAsync(bnpart, 0, 64 * 256 * 4, stream);

  k_prep<<<1, 256, 0, stream>>>(W, att_src, att_dst, Bext);

  int ntiles = (N + 63) / 64;
  int rsize = (N + NR - 1) / NR;
  // Fused: gemm (1024 blocks, no LDS) + count_rank (2048 blocks) in one launch
  k_gemm_count<<<GEMM_BLOCKS + COUNT_BLOCKS, 256, 0, stream>>>(
      x, Bext, hb, a_s, a_d, N, ntiles, ei, cnt, rank, E, rsize);

  int nb = (N + 255) / 256;
  k_scan1<<<nb, 256, 0, stream>>>(cnt, incl, bsum, N);
  k_scan2<<<1, 512, 0, stream>>>(bsum, nb);
  k_scan3<<<nb, 256, 0, stream>>>(cnt, incl, bsum, offs, N, E);

  k_scatter_rank<<<2048, 256, 0, stream>>>(ei, offs, rank, ssrc, E, rsize);

  k_agg<<<(N + 3) / 4, 256, 0, stream>>>(hb, a_s, a_d, offs, ssrc, bias, preb, bnpart, N);

  k_bnfinal<<<1, 128, 0, stream>>>(bnpart, gamma, beta, sc, sh, N);

  int npair2 = N * 32;  // N*64 u32 pairs / 2 per thread
  k_bnapply<<<(npair2 + 255) / 256, 256, 0, stream>>>(preb, out, sc, sh, npair2);
}

// Round 14
// 237.741 us; speedup vs baseline: 1.1161x; 1.1161x over previous
//
#include <hip/hip_runtime.h>

#define NEG 0.2f
#define MAXD 128
#define NR 8
#define GEMM_BLOCKS 1024
#define COUNT_BLOCKS 2048

__device__ __forceinline__ float lrelu(float v) { return v > 0.f ? v : NEG * v; }

// round-to-nearest-even fp32 -> bf16 (returns low 16 bits)
__device__ __forceinline__ unsigned f2bf(float f) {
  unsigned u = __float_as_uint(f);
  u = (u + 0x7FFFu + ((u >> 16) & 1u)) >> 16;
  return u;
}
__device__ __forceinline__ float bf_lo(unsigned u) { return __uint_as_float(u << 16); }
__device__ __forceinline__ float bf_hi(unsigned u) { return __uint_as_float(u & 0xFFFF0000u); }

typedef __attribute__((ext_vector_type(8))) short bf16x8;
typedef __attribute__((ext_vector_type(4))) float f32x4;

// ---- Kernel 0: build Bext (bf16, MFMA-fragment order); 9 grid-strided blocks ----
__global__ __launch_bounds__(256) void k_prep(const float* __restrict__ W,
                                              const float* __restrict__ att_src,
                                              const float* __restrict__ att_dst,
                                              unsigned short* __restrict__ Bext) {
  for (int id = blockIdx.x * 256 + threadIdx.x; id < 9 * 4 * 64 * 8; id += gridDim.x * 256) {
    int j = id & 7, lane = (id >> 3) & 63, kb = (id >> 9) & 3, ct = id >> 11;
    int k = kb * 32 + (lane >> 4) * 8 + j;
    int c = ct * 16 + (lane & 15);
    float v;
    if (c < 128) {
      v = W[k * 128 + c];
    } else {
      int slot = c - 128;
      int hd = slot & 3;
      const float* att = (slot < 4) ? att_src : att_dst;
      float s = 0.f;
      for (int jj = 0; jj < 32; ++jj) s = fmaf(W[k * 128 + hd * 32 + jj], att[hd * 32 + jj], s);
      v = s;
    }
    Bext[id] = (unsigned short)f2bf(v);
  }
}

// ---- Fused kernel, chunk-interleaved roles (8-block chunks keep &7 XCD pinning) ----
// chunk%3==0 -> GEMM (128 chunks = 1024 blocks); else -> count (256 chunks = 2048 blocks).
// Interleaved dispatch order co-schedules both paths on every CU from t=0.
__global__ __launch_bounds__(256) void k_gemm_count(
    const float* __restrict__ x, const unsigned short* __restrict__ Bext,
    unsigned* __restrict__ hb, float* __restrict__ a_s, float* __restrict__ a_d,
    int N, int ntiles,
    const int* __restrict__ ei, int* __restrict__ cnt, int* __restrict__ rank,
    int E, int rsize)
{
  const int tid = threadIdx.x;
  const int chunk = blockIdx.x >> 3;
  if (chunk % 3 == 0) {
    // ================= GEMM path =================
    const int vb = (chunk / 3) * 8 + (blockIdx.x & 7);   // [0,1024)
    const bf16x8* Bfrag = reinterpret_cast<const bf16x8*>(Bext);
    const int w = tid >> 6, lane = tid & 63;
    const int r16 = lane & 15, g = lane >> 4;
    for (int tile = vb; tile < ntiles; tile += GEMM_BLOCKS) {
      int n0 = tile * 64 + w * 16;
      int rowc = min(n0 + r16, N - 1);
      const float* xp = x + (size_t)rowc * 128 + g * 8;
      bf16x8 afr[4];
#pragma unroll
      for (int kb = 0; kb < 4; ++kb) {
        float4 lo = *reinterpret_cast<const float4*>(xp + kb * 32);
        float4 hi = *reinterpret_cast<const float4*>(xp + kb * 32 + 4);
        bf16x8 t;
        t[0] = (short)f2bf(lo.x); t[1] = (short)f2bf(lo.y);
        t[2] = (short)f2bf(lo.z); t[3] = (short)f2bf(lo.w);
        t[4] = (short)f2bf(hi.x); t[5] = (short)f2bf(hi.y);
        t[6] = (short)f2bf(hi.z); t[7] = (short)f2bf(hi.w);
        afr[kb] = t;
      }
#pragma unroll
      for (int ct = 0; ct < 9; ++ct) {
        f32x4 acc = {0.f, 0.f, 0.f, 0.f};
#pragma unroll
        for (int kb = 0; kb < 4; ++kb) {
          bf16x8 bfr = Bfrag[(ct * 4 + kb) * 64 + lane];
          acc = __builtin_amdgcn_mfma_f32_16x16x32_bf16(afr[kb], bfr, acc, 0, 0, 0);
        }
        if (ct < 8) {
#pragma unroll
          for (int r = 0; r < 4; ++r) {
            int orow = n0 + g * 4 + r;
            unsigned b = f2bf(acc[r]);
            unsigned partner = __shfl_xor(b, 1);
            if (((lane & 1) == 0) && orow < N)
              hb[(size_t)orow * 64 + ct * 8 + (r16 >> 1)] = b | (partner << 16);
          }
        } else {
#pragma unroll
          for (int r = 0; r < 4; ++r) {
            int orow = n0 + g * 4 + r;
            if (r16 < 8 && orow < N) {
              if (r16 < 4) a_s[orow * 4 + r16] = acc[r];
              else         a_d[orow * 4 + (r16 - 4)] = acc[r];
            }
          }
        }
      }
    }
  } else {
    // ================= count+rank path (XCD-pinned by bid&7) =================
    const int r = blockIdx.x & 7;
    const int lo = r * rsize, hi = lo + rsize;
    const int cidx = chunk - 1 - (chunk / 3);            // [0,256)
    const int gtid = cidx * 256 + tid;
    const int gstride = (COUNT_BLOCKS >> 3) * 256;
    const int nquad = E >> 2;
    const int4* dst4 = reinterpret_cast<const int4*>(ei + E);
    for (int q = gtid; q < nquad; q += gstride) {
      int4 d = dst4[q];
      int e0 = q << 2;
      if (d.x >= lo && d.x < hi) rank[e0]     = atomicAdd(&cnt[d.x], 1);
      if (d.y >= lo && d.y < hi) rank[e0 + 1] = atomicAdd(&cnt[d.y], 1);
      if (d.z >= lo && d.z < hi) rank[e0 + 2] = atomicAdd(&cnt[d.z], 1);
      if (d.w >= lo && d.w < hi) rank[e0 + 3] = atomicAdd(&cnt[d.w], 1);
    }
    for (int e = (nquad << 2) + gtid; e < E; e += gstride) {
      int d = ei[E + e];
      if (d >= lo && d < hi) rank[e] = atomicAdd(&cnt[d], 1);
    }
  }
}

// ---- Scan (3 kernels) ----
__global__ __launch_bounds__(256) void k_scan1(const int* __restrict__ cnt, int* __restrict__ incl,
                                               int* __restrict__ bsum, int N) {
  __shared__ int sm[256];
  int i = blockIdx.x * 256 + threadIdx.x;
  int v = (i < N) ? cnt[i] : 0;
  sm[threadIdx.x] = v;
  __syncthreads();
  for (int off = 1; off < 256; off <<= 1) {
    int t = (threadIdx.x >= off) ? sm[threadIdx.x - off] : 0;
    __syncthreads();
    sm[threadIdx.x] += t;
    __syncthreads();
  }
  if (i < N) incl[i] = sm[threadIdx.x];
  if (threadIdx.x == 255) bsum[blockIdx.x] = sm[255];
}

__global__ __launch_bounds__(512) void k_scan2(int* __restrict__ bsum, int nb) {
  __shared__ int sm[512];
  int v = (threadIdx.x < nb) ? bsum[threadIdx.x] : 0;
  sm[threadIdx.x] = v;
  __syncthreads();
  for (int off = 1; off < 512; off <<= 1) {
    int t = (threadIdx.x >= off) ? sm[threadIdx.x - off] : 0;
    __syncthreads();
    sm[threadIdx.x] += t;
    __syncthreads();
  }
  if (threadIdx.x < nb) bsum[threadIdx.x] = sm[threadIdx.x];
}

__global__ __launch_bounds__(256) void k_scan3(const int* __restrict__ cnt, const int* __restrict__ incl,
                                               const int* __restrict__ bsum, int* __restrict__ offs,
                                               int N, int E) {
  int i = blockIdx.x * 256 + threadIdx.x;
  if (i < N) {
    int base = (blockIdx.x > 0) ? bsum[blockIdx.x - 1] : 0;
    offs[i] = base + incl[i] - cnt[i];
  }
  if (i == 0) offs[N] = E;
}

// ---- XCD-pinned ATOMIC-FREE scatter: ssrc[offs[d]+rank[e]] = src[e] ----
__global__ __launch_bounds__(256) void k_scatter_rank(const int* __restrict__ ei,
                                                      const int* __restrict__ offs,
                                                      const int* __restrict__ rank,
                                                      int* __restrict__ ssrc, int E, int rsize) {
  const int r = blockIdx.x & 7;
  const int lo = r * rsize, hi = lo + rsize;
  const int gtid = (blockIdx.x >> 3) * 256 + threadIdx.x;
  const int gstride = (gridDim.x >> 3) * 256;
  const int nquad = E >> 2;
  const int4* dst4 = reinterpret_cast<const int4*>(ei + E);
  for (int q = gtid; q < nquad; q += gstride) {
    int4 d = dst4[q];
    int e0 = q << 2;
    if (d.x >= lo && d.x < hi) ssrc[offs[d.x] + rank[e0]]     = ei[e0];
    if (d.y >= lo && d.y < hi) ssrc[offs[d.y] + rank[e0 + 1]] = ei[e0 + 1];
    if (d.z >= lo && d.z < hi) ssrc[offs[d.z] + rank[e0 + 2]] = ei[e0 + 2];
    if (d.w >= lo && d.w < hi) ssrc[offs[d.w] + rank[e0 + 3]] = ei[e0 + 3];
  }
  for (int e = (nquad << 2) + gtid; e < E; e += gstride) {
    int d = ei[E + e];
    if (d >= lo && d < hi) ssrc[offs[d] + rank[e]] = ei[e];
  }
}

// ---- k_agg: per-node softmax + aggregation + bias + ELU + fused BN partials ----
__global__ __launch_bounds__(256) void k_agg(
    const unsigned* __restrict__ hb, const float* __restrict__ a_s, const float* __restrict__ a_d,
    const int* __restrict__ offs, const int* __restrict__ ssrc,
    const float* __restrict__ bias, unsigned* __restrict__ preb,
    float* __restrict__ bnpart, int N)
{
  __shared__ float al[4][MAXD][4];   // per-edge alpha (pre-scaled), per head
  __shared__ int   ls[4][MAXD];      // per-edge src id
  __shared__ float sv[4][128];       // per-wave output row (post-ELU) for BN reduce
  const int wv = threadIdx.x >> 6;
  const int lane = threadIdx.x & 63;
  const int n = blockIdx.x * 4 + wv;

  if (n < N) {
    const int hsel = lane >> 4;
    const int start = offs[n], end = offs[n + 1];
    const int deg = end - start;
    const int jm = deg < MAXD ? deg : MAXD;
    float4 adv = *reinterpret_cast<const float4*>(&a_d[n * 4]);
    float4 asv = *reinterpret_cast<const float4*>(&a_s[n * 4]);
    float e0 = __expf(lrelu(asv.x + adv.x));
    float e1 = __expf(lrelu(asv.y + adv.y));
    float e2 = __expf(lrelu(asv.z + adv.z));
    float e3 = __expf(lrelu(asv.w + adv.w));
    float p0 = 0.f, p1 = 0.f, p2 = 0.f, p3 = 0.f;
    for (int j = lane; j < deg; j += 64) {
      int s = ssrc[start + j];
      float4 av = *reinterpret_cast<const float4*>(&a_s[s * 4]);
      float x0 = __expf(lrelu(av.x + adv.x));
      float x1 = __expf(lrelu(av.y + adv.y));
      float x2 = __expf(lrelu(av.z + adv.z));
      float x3 = __expf(lrelu(av.w + adv.w));
      p0 += x0; p1 += x1; p2 += x2; p3 += x3;
      if (j < MAXD) {
        float4 t = make_float4(x0, x1, x2, x3);
        *reinterpret_cast<float4*>(&al[wv][j][0]) = t;
        ls[wv][j] = s;
      }
    }
#pragma unroll
    for (int off = 32; off >= 1; off >>= 1) {
      p0 += __shfl_xor(p0, off);
      p1 += __shfl_xor(p1, off);
      p2 += __shfl_xor(p2, off);
      p3 += __shfl_xor(p3, off);
    }
    float rden0 = 1.f / (p0 + e0), rden1 = 1.f / (p1 + e1);
    float rden2 = 1.f / (p2 + e2), rden3 = 1.f / (p3 + e3);
    for (int j = lane; j < jm; j += 64) {
      float4 t = *reinterpret_cast<float4*>(&al[wv][j][0]);
      t.x *= rden0; t.y *= rden1; t.z *= rden2; t.w *= rden3;
      *reinterpret_cast<float4*>(&al[wv][j][0]) = t;
    }
    float ad_c = (hsel < 2) ? (hsel == 0 ? adv.x : adv.y) : (hsel == 2 ? adv.z : adv.w);
    float rden = (hsel < 2) ? (hsel == 0 ? rden0 : rden1) : (hsel == 2 ? rden2 : rden3);
    float esf = (hsel < 2) ? (hsel == 0 ? e0 : e1) : (hsel == 2 ? e2 : e3);
    unsigned us = hb[(size_t)n * 64 + lane];
    float wself = esf * rden;
    float acc0 = wself * bf_lo(us);
    float acc1 = wself * bf_hi(us);
    int j = 0;
    for (; j + 8 <= jm; j += 8) {
      int4 sA = *reinterpret_cast<int4*>(&ls[wv][j]);
      int4 sB = *reinterpret_cast<int4*>(&ls[wv][j + 4]);
      unsigned u0 = hb[(size_t)sA.x * 64 + lane];
      unsigned u1 = hb[(size_t)sA.y * 64 + lane];
      unsigned u2 = hb[(size_t)sA.z * 64 + lane];
      unsigned u3 = hb[(size_t)sA.w * 64 + lane];
      unsigned u4 = hb[(size_t)sB.x * 64 + lane];
      unsigned u5 = hb[(size_t)sB.y * 64 + lane];
      unsigned u6 = hb[(size_t)sB.z * 64 + lane];
      unsigned u7 = hb[(size_t)sB.w * 64 + lane];
      float w0 = al[wv][j][hsel];
      float w1 = al[wv][j + 1][hsel];
      float w2 = al[wv][j + 2][hsel];
      float w3 = al[wv][j + 3][hsel];
      float w4 = al[wv][j + 4][hsel];
      float w5 = al[wv][j + 5][hsel];
      float w6 = al[wv][j + 6][hsel];
      float w7 = al[wv][j + 7][hsel];
      acc0 = fmaf(w0, bf_lo(u0), acc0);
      acc1 = fmaf(w0, bf_hi(u0), acc1);
      acc0 = fmaf(w1, bf_lo(u1), acc0);
      acc1 = fmaf(w1, bf_hi(u1), acc1);
      acc0 = fmaf(w2, bf_lo(u2), acc0);
      acc1 = fmaf(w2, bf_hi(u2), acc1);
      acc0 = fmaf(w3, bf_lo(u3), acc0);
      acc1 = fmaf(w3, bf_hi(u3), acc1);
      acc0 = fmaf(w4, bf_lo(u4), acc0);
      acc1 = fmaf(w4, bf_hi(u4), acc1);
      acc0 = fmaf(w5, bf_lo(u5), acc0);
      acc1 = fmaf(w5, bf_hi(u5), acc1);
      acc0 = fmaf(w6, bf_lo(u6), acc0);
      acc1 = fmaf(w6, bf_hi(u6), acc1);
      acc0 = fmaf(w7, bf_lo(u7), acc0);
      acc1 = fmaf(w7, bf_hi(u7), acc1);
    }
    for (; j + 4 <= jm; j += 4) {
      int4 s4 = *reinterpret_cast<int4*>(&ls[wv][j]);
      unsigned u0 = hb[(size_t)s4.x * 64 + lane];
      unsigned u1 = hb[(size_t)s4.y * 64 + lane];
      unsigned u2 = hb[(size_t)s4.z * 64 + lane];
      unsigned u3 = hb[(size_t)s4.w * 64 + lane];
      float w0 = al[wv][j][hsel];
      float w1 = al[wv][j + 1][hsel];
      float w2 = al[wv][j + 2][hsel];
      float w3 = al[wv][j + 3][hsel];
      acc0 = fmaf(w0, bf_lo(u0), acc0);
      acc1 = fmaf(w0, bf_hi(u0), acc1);
      acc0 = fmaf(w1, bf_lo(u1), acc0);
      acc1 = fmaf(w1, bf_hi(u1), acc1);
      acc0 = fmaf(w2, bf_lo(u2), acc0);
      acc1 = fmaf(w2, bf_hi(u2), acc1);
      acc0 = fmaf(w3, bf_lo(u3), acc0);
      acc1 = fmaf(w3, bf_hi(u3), acc1);
    }
    for (; j < jm; ++j) {
      int s = ls[wv][j];
      float w = al[wv][j][hsel];
      unsigned u = hb[(size_t)s * 64 + lane];
      acc0 = fmaf(w, bf_lo(u), acc0);
      acc1 = fmaf(w, bf_hi(u), acc1);
    }
    for (int jj = MAXD; jj < deg; ++jj) {
      int s = ssrc[start + jj];
      float q = a_s[s * 4 + hsel];
      unsigned u = hb[(size_t)s * 64 + lane];
      float w = __expf(lrelu(q + ad_c)) * rden;
      acc0 = fmaf(w, bf_lo(u), acc0);
      acc1 = fmaf(w, bf_hi(u), acc1);
    }
    float2 bv = *reinterpret_cast<const float2*>(&bias[2 * lane]);
    float o0 = acc0 + bv.x;
    float o1 = acc1 + bv.y;
    o0 = o0 > 0.f ? o0 : expm1f(o0);
    o1 = o1 > 0.f ? o1 : expm1f(o1);
    preb[(size_t)n * 64 + lane] = f2bf(o0) | (f2bf(o1) << 16);
    sv[wv][2 * lane] = o0;
    sv[wv][2 * lane + 1] = o1;
  } else {
    sv[wv][2 * lane] = 0.f;
    sv[wv][2 * lane + 1] = 0.f;
  }
  __syncthreads();
  int t = threadIdx.x;
  if (t < 128) {
    float s = 0.f, q = 0.f;
#pragma unroll
    for (int w2 = 0; w2 < 4; ++w2) {
      float v = sv[w2][t];
      s += v;
      q = fmaf(v, v, q);
    }
    float* slot = bnpart + (size_t)(blockIdx.x & 63) * 256;
    atomicAdd(&slot[t], s);
    atomicAdd(&slot[128 + t], q);
  }
}

// ---- BN scale/shift from partials ----
__global__ void k_bnfinal(const float* __restrict__ bnpart,
                          const float* __restrict__ gamma, const float* __restrict__ beta,
                          float* __restrict__ sc, float* __restrict__ sh, int N) {
  int c = threadIdx.x;
  float s = 0.f, q = 0.f;
  for (int p = 0; p < 64; ++p) {
    s += bnpart[p * 256 + c];
    q += bnpart[p * 256 + 128 + c];
  }
  float invn = 1.f / (float)N;
  float mean = s * invn;
  float var = q * invn - mean * mean;
  float scl = gamma[c] * rsqrtf(var + 1e-5f);
  sc[c] = scl;
  sh[c] = beta[c] - mean * scl;
}

// ---- apply BN: read packed bf16 pre, write fp32 out ----
__global__ __launch_bounds__(256) void k_bnapply(const unsigned* __restrict__ preb,
                                                 float* __restrict__ out,
                                                 const float* __restrict__ sc,
                                                 const float* __restrict__ sh, int npair2) {
  int i = blockIdx.x * blockDim.x + threadIdx.x;
  if (i >= npair2) return;
  uint2 u = reinterpret_cast<const uint2*>(preb)[i];
  int p0 = i * 2;
  int c0 = (p0 & 63) * 2;
  float4 scv = *reinterpret_cast<const float4*>(&sc[c0]);
  float4 shv = *reinterpret_cast<const float4*>(&sh[c0]);
  float4 v;
  v.x = fmaf(bf_lo(u.x), scv.x, shv.x);
  v.y = fmaf(bf_hi(u.x), scv.y, shv.y);
  v.z = fmaf(bf_lo(u.y), scv.z, shv.z);
  v.w = fmaf(bf_hi(u.y), scv.w, shv.w);
  reinterpret_cast<float4*>(out)[i] = v;
}

extern "C" void kernel_launch(void* const* d_in, const int* in_sizes, int n_in,
                              void* d_out, int out_size, void* d_ws, size_t ws_size,
                              hipStream_t stream) {
  const float* x = (const float*)d_in[0];
  const int* ei = (const int*)d_in[1];
  const float* W = (const float*)d_in[2];
  const float* att_src = (const float*)d_in[3];
  const float* att_dst = (const float*)d_in[4];
  const float* bias = (const float*)d_in[5];
  const float* gamma = (const float*)d_in[6];
  const float* beta = (const float*)d_in[7];
  float* out = (float*)d_out;

  const int N = in_sizes[0] / 128;
  const int E = in_sizes[1] / 2;

  char* ws = (char*)d_ws;
  size_t off = 0;
  auto alloc = [&](size_t bytes) {
    void* p = ws + off;
    off = (off + bytes + 255) & ~(size_t)255;
    return p;
  };
  unsigned* hb = (unsigned*)alloc((size_t)N * 64 * 4);
  float* a_s = (float*)alloc((size_t)N * 4 * 4);
  float* a_d = (float*)alloc((size_t)N * 4 * 4);
  int* cnt = (int*)alloc((size_t)N * 4);
  int* incl = (int*)alloc((size_t)N * 4);
  int* offs = (int*)alloc((size_t)(N + 1) * 4);
  int* bsum = (int*)alloc(512 * 4);
  int* rank = (int*)alloc((size_t)E * 4);
  int* ssrc = (int*)alloc((size_t)E * 4);
  unsigned* preb = (unsigned*)alloc((size_t)N * 64 * 4);
  float* bnpart = (float*)alloc(64 * 256 * 4);
  float* sc = (float*)alloc(128 * 4);
  float* sh = (float*)alloc(128 * 4);
  unsigned short* Bext = (unsigned short*)alloc(9 * 4 * 64 * 8 * 2);
  (void)n_in; (void)out_size; (void)ws_size;

  hipMemsetAsync(cnt, 0, (size_t)N * 4, stream);
  hipMemsetAsync(bnpart, 0, 64 * 256 * 4, stream);

  k_prep<<<9, 256, 0, stream>>>(W, att_src, att_dst, Bext);

  int ntiles = (N + 63) / 64;
  int rsize = (N + NR - 1) / NR;
  k_gemm_count<<<GEMM_BLOCKS + COUNT_BLOCKS, 256, 0, stream>>>(
      x, Bext, hb, a_s, a_d, N, ntiles, ei, cnt, rank, E, rsize);

  int nb = (N + 255) / 256;
  k_scan1<<<nb, 256, 0, stream>>>(cnt, incl, bsum, N);
  k_scan2<<<1, 512, 0, stream>>>(bsum, nb);
  k_scan3<<<nb, 256, 0, stream>>>(cnt, incl, bsum, offs, N, E);

  k_scatter_rank<<<2048, 256, 0, stream>>>(ei, offs, rank, ssrc, E, rsize);

  k_agg<<<(N + 3) / 4, 256, 0, stream>>>(hb, a_s, a_d, offs, ssrc, bias, preb, bnpart, N);

  k_bnfinal<<<1, 128, 0, stream>>>(bnpart, gamma, beta, sc, sh, N);

  int npair2 = N * 32;
  k_bnapply<<<(npair2 + 255) / 256, 256, 0, stream>>>(preb, out, sc, sh, npair2);
}

// Round 15
// 233.976 us; speedup vs baseline: 1.1340x; 1.0161x over previous
//
#include <hip/hip_runtime.h>

#define NEG 0.2f
#define MAXD 128
#define GEMM_BLOCKS 1024
#define COUNT_BLOCKS 2048

__device__ __forceinline__ float lrelu(float v) { return v > 0.f ? v : NEG * v; }

// round-to-nearest-even fp32 -> bf16 (returns low 16 bits)
__device__ __forceinline__ unsigned f2bf(float f) {
  unsigned u = __float_as_uint(f);
  u = (u + 0x7FFFu + ((u >> 16) & 1u)) >> 16;
  return u;
}
__device__ __forceinline__ float bf_lo(unsigned u) { return __uint_as_float(u << 16); }
__device__ __forceinline__ float bf_hi(unsigned u) { return __uint_as_float(u & 0xFFFF0000u); }

typedef __attribute__((ext_vector_type(8))) short bf16x8;
typedef __attribute__((ext_vector_type(4))) float f32x4;

// ---- Kernel 0: build Bext (bf16, MFMA-fragment order); 9 grid-strided blocks ----
__global__ __launch_bounds__(256) void k_prep(const float* __restrict__ W,
                                              const float* __restrict__ att_src,
                                              const float* __restrict__ att_dst,
                                              unsigned short* __restrict__ Bext) {
  for (int id = blockIdx.x * 256 + threadIdx.x; id < 9 * 4 * 64 * 8; id += gridDim.x * 256) {
    int j = id & 7, lane = (id >> 3) & 63, kb = (id >> 9) & 3, ct = id >> 11;
    int k = kb * 32 + (lane >> 4) * 8 + j;
    int c = ct * 16 + (lane & 15);
    float v;
    if (c < 128) {
      v = W[k * 128 + c];
    } else {
      int slot = c - 128;
      int hd = slot & 3;
      const float* att = (slot < 4) ? att_src : att_dst;
      float s = 0.f;
      for (int jj = 0; jj < 32; ++jj) s = fmaf(W[k * 128 + hd * 32 + jj], att[hd * 32 + jj], s);
      v = s;
    }
    Bext[id] = (unsigned short)f2bf(v);
  }
}

// ---- Fused kernel, chunk-interleaved roles (8-block chunks keep &7 XCD pinning) ----
// GEMM: chunk%3==0 (1024 blocks). COUNT: else (2048 blocks), EDGE-partitioned:
// XCD r owns edge region [r<<esh,(r+1)<<esh) -> dense rank writes from ONE XCD (no
// line bounce) + atomics into private cnt8[r][*] copy (stays in that XCD's L2).
__global__ __launch_bounds__(256) void k_gemm_count(
    const float* __restrict__ x, const unsigned short* __restrict__ Bext,
    unsigned* __restrict__ hb, float* __restrict__ a_s, float* __restrict__ a_d,
    int N, int ntiles,
    const int* __restrict__ ei, int* __restrict__ cnt8, int* __restrict__ rank,
    int E, int esh)
{
  const int tid = threadIdx.x;
  const int chunk = blockIdx.x >> 3;
  if (chunk % 3 == 0) {
    // ================= GEMM path =================
    const int vb = (chunk / 3) * 8 + (blockIdx.x & 7);   // [0,1024)
    const bf16x8* Bfrag = reinterpret_cast<const bf16x8*>(Bext);
    const int w = tid >> 6, lane = tid & 63;
    const int r16 = lane & 15, g = lane >> 4;
    for (int tile = vb; tile < ntiles; tile += GEMM_BLOCKS) {
      int n0 = tile * 64 + w * 16;
      int rowc = min(n0 + r16, N - 1);
      const float* xp = x + (size_t)rowc * 128 + g * 8;
      bf16x8 afr[4];
#pragma unroll
      for (int kb = 0; kb < 4; ++kb) {
        float4 lo = *reinterpret_cast<const float4*>(xp + kb * 32);
        float4 hi = *reinterpret_cast<const float4*>(xp + kb * 32 + 4);
        bf16x8 t;
        t[0] = (short)f2bf(lo.x); t[1] = (short)f2bf(lo.y);
        t[2] = (short)f2bf(lo.z); t[3] = (short)f2bf(lo.w);
        t[4] = (short)f2bf(hi.x); t[5] = (short)f2bf(hi.y);
        t[6] = (short)f2bf(hi.z); t[7] = (short)f2bf(hi.w);
        afr[kb] = t;
      }
#pragma unroll
      for (int ct = 0; ct < 9; ++ct) {
        f32x4 acc = {0.f, 0.f, 0.f, 0.f};
#pragma unroll
        for (int kb = 0; kb < 4; ++kb) {
          bf16x8 bfr = Bfrag[(ct * 4 + kb) * 64 + lane];
          acc = __builtin_amdgcn_mfma_f32_16x16x32_bf16(afr[kb], bfr, acc, 0, 0, 0);
        }
        if (ct < 8) {
#pragma unroll
          for (int r = 0; r < 4; ++r) {
            int orow = n0 + g * 4 + r;
            unsigned b = f2bf(acc[r]);
            unsigned partner = __shfl_xor(b, 1);
            if (((lane & 1) == 0) && orow < N)
              hb[(size_t)orow * 64 + ct * 8 + (r16 >> 1)] = b | (partner << 16);
          }
        } else {
#pragma unroll
          for (int r = 0; r < 4; ++r) {
            int orow = n0 + g * 4 + r;
            if (r16 < 8 && orow < N) {
              if (r16 < 4) a_s[orow * 4 + r16] = acc[r];
              else         a_d[orow * 4 + (r16 - 4)] = acc[r];
            }
          }
        }
      }
    }
  } else {
    // ================= count+rank path (edge-partitioned, XCD-private cnt8) =====
    const int r = blockIdx.x & 7;
    const int cidx = chunk - 1 - (chunk / 3);            // [0,256)
    const int qper = 1 << (esh - 2);                     // quads per region
    const int ebase = r << esh;
    int* cpriv = cnt8 + (size_t)r * N;
    for (int ql = cidx * 256 + tid; ql < qper; ql += 256 * 256) {
      int e0 = ebase + (ql << 2);
      if (e0 >= E) break;
      if (e0 + 3 < E) {
        int4 d = *reinterpret_cast<const int4*>(ei + E + e0);
        int4 rk;
        rk.x = atomicAdd(&cpriv[d.x], 1);
        rk.y = atomicAdd(&cpriv[d.y], 1);
        rk.z = atomicAdd(&cpriv[d.z], 1);
        rk.w = atomicAdd(&cpriv[d.w], 1);
        *reinterpret_cast<int4*>(rank + e0) = rk;        // dense 16B write, one XCD
      } else {
        for (int e = e0; e < E; ++e) {
          int d = ei[E + e];
          rank[e] = atomicAdd(&cpriv[d], 1);
        }
      }
    }
  }
}

// ---- Scan 1: per-node 8-way prefix over cnt8 (written back as sub-offsets) + block scan ----
__global__ __launch_bounds__(256) void k_scan1(int* __restrict__ cnt8, int* __restrict__ cnt,
                                               int* __restrict__ incl, int* __restrict__ bsum, int N) {
  __shared__ int sm[256];
  int i = blockIdx.x * 256 + threadIdx.x;
  int tot = 0;
  if (i < N) {
    int run = 0;
#pragma unroll
    for (int r = 0; r < 8; ++r) {
      int t = cnt8[(size_t)r * N + i];
      cnt8[(size_t)r * N + i] = run;   // exclusive prefix = per-region sub-offset
      run += t;
    }
    cnt[i] = run;
    tot = run;
  }
  sm[threadIdx.x] = tot;
  __syncthreads();
  for (int off = 1; off < 256; off <<= 1) {
    int t = (threadIdx.x >= off) ? sm[threadIdx.x - off] : 0;
    __syncthreads();
    sm[threadIdx.x] += t;
    __syncthreads();
  }
  if (i < N) incl[i] = sm[threadIdx.x];
  if (threadIdx.x == 255) bsum[blockIdx.x] = sm[255];
}

__global__ __launch_bounds__(512) void k_scan2(int* __restrict__ bsum, int nb) {
  __shared__ int sm[512];
  int v = (threadIdx.x < nb) ? bsum[threadIdx.x] : 0;
  sm[threadIdx.x] = v;
  __syncthreads();
  for (int off = 1; off < 512; off <<= 1) {
    int t = (threadIdx.x >= off) ? sm[threadIdx.x - off] : 0;
    __syncthreads();
    sm[threadIdx.x] += t;
    __syncthreads();
  }
  if (threadIdx.x < nb) bsum[threadIdx.x] = sm[threadIdx.x];
}

__global__ __launch_bounds__(256) void k_scan3(const int* __restrict__ cnt, const int* __restrict__ incl,
                                               const int* __restrict__ bsum, int* __restrict__ offs,
                                               int N, int E) {
  int i = blockIdx.x * 256 + threadIdx.x;
  if (i < N) {
    int base = (blockIdx.x > 0) ? bsum[blockIdx.x - 1] : 0;
    offs[i] = base + incl[i] - cnt[i];
  }
  if (i == 0) offs[N] = E;
}

// ---- XCD-pinned (by dst) ATOMIC-FREE scatter: pos = offs[d] + suboff[e>>esh][d] + rank[e] ----
__global__ __launch_bounds__(256) void k_scatter_rank(const int* __restrict__ ei,
                                                      const int* __restrict__ offs,
                                                      const int* __restrict__ cnt8,
                                                      const int* __restrict__ rank,
                                                      int* __restrict__ ssrc, int E, int rsize,
                                                      int esh, int N) {
  const int r = blockIdx.x & 7;
  const int lo = r * rsize, hi = lo + rsize;
  const int gtid = (blockIdx.x >> 3) * 256 + threadIdx.x;
  const int gstride = (gridDim.x >> 3) * 256;
  const int nquad = E >> 2;
  const int4* dst4 = reinterpret_cast<const int4*>(ei + E);
  for (int q = gtid; q < nquad; q += gstride) {
    int4 d = dst4[q];
    int e0 = q << 2;
    if (d.x >= lo && d.x < hi) ssrc[offs[d.x] + cnt8[(size_t)(e0 >> esh) * N + d.x] + rank[e0]]         = ei[e0];
    if (d.y >= lo && d.y < hi) ssrc[offs[d.y] + cnt8[(size_t)((e0+1) >> esh) * N + d.y] + rank[e0 + 1]] = ei[e0 + 1];
    if (d.z >= lo && d.z < hi) ssrc[offs[d.z] + cnt8[(size_t)((e0+2) >> esh) * N + d.z] + rank[e0 + 2]] = ei[e0 + 2];
    if (d.w >= lo && d.w < hi) ssrc[offs[d.w] + cnt8[(size_t)((e0+3) >> esh) * N + d.w] + rank[e0 + 3]] = ei[e0 + 3];
  }
  for (int e = (nquad << 2) + gtid; e < E; e += gstride) {
    int d = ei[E + e];
    if (d >= lo && d < hi) ssrc[offs[d] + cnt8[(size_t)(e >> esh) * N + d] + rank[e]] = ei[e];
  }
}

// ---- k_agg: per-node softmax + aggregation + bias + ELU + fused BN partials ----
__global__ __launch_bounds__(256) void k_agg(
    const unsigned* __restrict__ hb, const float* __restrict__ a_s, const float* __restrict__ a_d,
    const int* __restrict__ offs, const int* __restrict__ ssrc,
    const float* __restrict__ bias, unsigned* __restrict__ preb,
    float* __restrict__ bnpart, int N)
{
  __shared__ float al[4][MAXD][4];   // per-edge alpha (pre-scaled), per head
  __shared__ int   ls[4][MAXD];      // per-edge src id
  __shared__ float sv[4][128];       // per-wave output row (post-ELU) for BN reduce
  const int wv = threadIdx.x >> 6;
  const int lane = threadIdx.x & 63;
  const int n = blockIdx.x * 4 + wv;

  if (n < N) {
    const int hsel = lane >> 4;
    const int start = offs[n], end = offs[n + 1];
    const int deg = end - start;
    const int jm = deg < MAXD ? deg : MAXD;
    float4 adv = *reinterpret_cast<const float4*>(&a_d[n * 4]);
    float4 asv = *reinterpret_cast<const float4*>(&a_s[n * 4]);
    float e0 = __expf(lrelu(asv.x + adv.x));
    float e1 = __expf(lrelu(asv.y + adv.y));
    float e2 = __expf(lrelu(asv.z + adv.z));
    float e3 = __expf(lrelu(asv.w + adv.w));
    float p0 = 0.f, p1 = 0.f, p2 = 0.f, p3 = 0.f;
    for (int j = lane; j < deg; j += 64) {
      int s = ssrc[start + j];
      float4 av = *reinterpret_cast<const float4*>(&a_s[s * 4]);
      float x0 = __expf(lrelu(av.x + adv.x));
      float x1 = __expf(lrelu(av.y + adv.y));
      float x2 = __expf(lrelu(av.z + adv.z));
      float x3 = __expf(lrelu(av.w + adv.w));
      p0 += x0; p1 += x1; p2 += x2; p3 += x3;
      if (j < MAXD) {
        float4 t = make_float4(x0, x1, x2, x3);
        *reinterpret_cast<float4*>(&al[wv][j][0]) = t;
        ls[wv][j] = s;
      }
    }
#pragma unroll
    for (int off = 32; off >= 1; off >>= 1) {
      p0 += __shfl_xor(p0, off);
      p1 += __shfl_xor(p1, off);
      p2 += __shfl_xor(p2, off);
      p3 += __shfl_xor(p3, off);
    }
    float rden0 = 1.f / (p0 + e0), rden1 = 1.f / (p1 + e1);
    float rden2 = 1.f / (p2 + e2), rden3 = 1.f / (p3 + e3);
    for (int j = lane; j < jm; j += 64) {
      float4 t = *reinterpret_cast<float4*>(&al[wv][j][0]);
      t.x *= rden0; t.y *= rden1; t.z *= rden2; t.w *= rden3;
      *reinterpret_cast<float4*>(&al[wv][j][0]) = t;
    }
    float ad_c = (hsel < 2) ? (hsel == 0 ? adv.x : adv.y) : (hsel == 2 ? adv.z : adv.w);
    float rden = (hsel < 2) ? (hsel == 0 ? rden0 : rden1) : (hsel == 2 ? rden2 : rden3);
    float esf = (hsel < 2) ? (hsel == 0 ? e0 : e1) : (hsel == 2 ? e2 : e3);
    unsigned us = hb[(size_t)n * 64 + lane];
    float wself = esf * rden;
    float acc0 = wself * bf_lo(us);
    float acc1 = wself * bf_hi(us);
    int j = 0;
    for (; j + 8 <= jm; j += 8) {
      int4 sA = *reinterpret_cast<int4*>(&ls[wv][j]);
      int4 sB = *reinterpret_cast<int4*>(&ls[wv][j + 4]);
      unsigned u0 = hb[(size_t)sA.x * 64 + lane];
      unsigned u1 = hb[(size_t)sA.y * 64 + lane];
      unsigned u2 = hb[(size_t)sA.z * 64 + lane];
      unsigned u3 = hb[(size_t)sA.w * 64 + lane];
      unsigned u4 = hb[(size_t)sB.x * 64 + lane];
      unsigned u5 = hb[(size_t)sB.y * 64 + lane];
      unsigned u6 = hb[(size_t)sB.z * 64 + lane];
      unsigned u7 = hb[(size_t)sB.w * 64 + lane];
      float w0 = al[wv][j][hsel];
      float w1 = al[wv][j + 1][hsel];
      float w2 = al[wv][j + 2][hsel];
      float w3 = al[wv][j + 3][hsel];
      float w4 = al[wv][j + 4][hsel];
      float w5 = al[wv][j + 5][hsel];
      float w6 = al[wv][j + 6][hsel];
      float w7 = al[wv][j + 7][hsel];
      acc0 = fmaf(w0, bf_lo(u0), acc0);
      acc1 = fmaf(w0, bf_hi(u0), acc1);
      acc0 = fmaf(w1, bf_lo(u1), acc0);
      acc1 = fmaf(w1, bf_hi(u1), acc1);
      acc0 = fmaf(w2, bf_lo(u2), acc0);
      acc1 = fmaf(w2, bf_hi(u2), acc1);
      acc0 = fmaf(w3, bf_lo(u3), acc0);
      acc1 = fmaf(w3, bf_hi(u3), acc1);
      acc0 = fmaf(w4, bf_lo(u4), acc0);
      acc1 = fmaf(w4, bf_hi(u4), acc1);
      acc0 = fmaf(w5, bf_lo(u5), acc0);
      acc1 = fmaf(w5, bf_hi(u5), acc1);
      acc0 = fmaf(w6, bf_lo(u6), acc0);
      acc1 = fmaf(w6, bf_hi(u6), acc1);
      acc0 = fmaf(w7, bf_lo(u7), acc0);
      acc1 = fmaf(w7, bf_hi(u7), acc1);
    }
    for (; j + 4 <= jm; j += 4) {
      int4 s4 = *reinterpret_cast<int4*>(&ls[wv][j]);
      unsigned u0 = hb[(size_t)s4.x * 64 + lane];
      unsigned u1 = hb[(size_t)s4.y * 64 + lane];
      unsigned u2 = hb[(size_t)s4.z * 64 + lane];
      unsigned u3 = hb[(size_t)s4.w * 64 + lane];
      float w0 = al[wv][j][hsel];
      float w1 = al[wv][j + 1][hsel];
      float w2 = al[wv][j + 2][hsel];
      float w3 = al[wv][j + 3][hsel];
      acc0 = fmaf(w0, bf_lo(u0), acc0);
      acc1 = fmaf(w0, bf_hi(u0), acc1);
      acc0 = fmaf(w1, bf_lo(u1), acc0);
      acc1 = fmaf(w1, bf_hi(u1), acc1);
      acc0 = fmaf(w2, bf_lo(u2), acc0);
      acc1 = fmaf(w2, bf_hi(u2), acc1);
      acc0 = fmaf(w3, bf_lo(u3), acc0);
      acc1 = fmaf(w3, bf_hi(u3), acc1);
    }
    for (; j < jm; ++j) {
      int s = ls[wv][j];
      float w = al[wv][j][hsel];
      unsigned u = hb[(size_t)s * 64 + lane];
      acc0 = fmaf(w, bf_lo(u), acc0);
      acc1 = fmaf(w, bf_hi(u), acc1);
    }
    for (int jj = MAXD; jj < deg; ++jj) {
      int s = ssrc[start + jj];
      float q = a_s[s * 4 + hsel];
      unsigned u = hb[(size_t)s * 64 + lane];
      float w = __expf(lrelu(q + ad_c)) * rden;
      acc0 = fmaf(w, bf_lo(u), acc0);
      acc1 = fmaf(w, bf_hi(u), acc1);
    }
    float2 bv = *reinterpret_cast<const float2*>(&bias[2 * lane]);
    float o0 = acc0 + bv.x;
    float o1 = acc1 + bv.y;
    o0 = o0 > 0.f ? o0 : expm1f(o0);
    o1 = o1 > 0.f ? o1 : expm1f(o1);
    preb[(size_t)n * 64 + lane] = f2bf(o0) | (f2bf(o1) << 16);
    sv[wv][2 * lane] = o0;
    sv[wv][2 * lane + 1] = o1;
  } else {
    sv[wv][2 * lane] = 0.f;
    sv[wv][2 * lane + 1] = 0.f;
  }
  __syncthreads();
  int t = threadIdx.x;
  if (t < 128) {
    float s = 0.f, q = 0.f;
#pragma unroll
    for (int w2 = 0; w2 < 4; ++w2) {
      float v = sv[w2][t];
      s += v;
      q = fmaf(v, v, q);
    }
    float* slot = bnpart + (size_t)(blockIdx.x & 63) * 256;
    atomicAdd(&slot[t], s);
    atomicAdd(&slot[128 + t], q);
  }
}

// ---- BN scale/shift from partials ----
__global__ void k_bnfinal(const float* __restrict__ bnpart,
                          const float* __restrict__ gamma, const float* __restrict__ beta,
                          float* __restrict__ sc, float* __restrict__ sh, int N) {
  int c = threadIdx.x;
  float s = 0.f, q = 0.f;
  for (int p = 0; p < 64; ++p) {
    s += bnpart[p * 256 + c];
    q += bnpart[p * 256 + 128 + c];
  }
  float invn = 1.f / (float)N;
  float mean = s * invn;
  float var = q * invn - mean * mean;
  float scl = gamma[c] * rsqrtf(var + 1e-5f);
  sc[c] = scl;
  sh[c] = beta[c] - mean * scl;
}

// ---- apply BN: read packed bf16 pre, write fp32 out ----
__global__ __launch_bounds__(256) void k_bnapply(const unsigned* __restrict__ preb,
                                                 float* __restrict__ out,
                                                 const float* __restrict__ sc,
                                                 const float* __restrict__ sh, int npair2) {
  int i = blockIdx.x * blockDim.x + threadIdx.x;
  if (i >= npair2) return;
  uint2 u = reinterpret_cast<const uint2*>(preb)[i];
  int p0 = i * 2;
  int c0 = (p0 & 63) * 2;
  float4 scv = *reinterpret_cast<const float4*>(&sc[c0]);
  float4 shv = *reinterpret_cast<const float4*>(&sh[c0]);
  float4 v;
  v.x = fmaf(bf_lo(u.x), scv.x, shv.x);
  v.y = fmaf(bf_hi(u.x), scv.y, shv.y);
  v.z = fmaf(bf_lo(u.y), scv.z, shv.z);
  v.w = fmaf(bf_hi(u.y), scv.w, shv.w);
  reinterpret_cast<float4*>(out)[i] = v;
}

extern "C" void kernel_launch(void* const* d_in, const int* in_sizes, int n_in,
                              void* d_out, int out_size, void* d_ws, size_t ws_size,
                              hipStream_t stream) {
  const float* x = (const float*)d_in[0];
  const int* ei = (const int*)d_in[1];
  const float* W = (const float*)d_in[2];
  const float* att_src = (const float*)d_in[3];
  const float* att_dst = (const float*)d_in[4];
  const float* bias = (const float*)d_in[5];
  const float* gamma = (const float*)d_in[6];
  const float* beta = (const float*)d_in[7];
  float* out = (float*)d_out;

  const int N = in_sizes[0] / 128;
  const int E = in_sizes[1] / 2;

  char* ws = (char*)d_ws;
  size_t off = 0;
  auto alloc = [&](size_t bytes) {
    void* p = ws + off;
    off = (off + bytes + 255) & ~(size_t)255;
    return p;
  };
  unsigned* hb = (unsigned*)alloc((size_t)N * 64 * 4);
  float* a_s = (float*)alloc((size_t)N * 4 * 4);
  float* a_d = (float*)alloc((size_t)N * 4 * 4);
  int* cnt = (int*)alloc((size_t)N * 4);
  int* incl = (int*)alloc((size_t)N * 4);
  int* offs = (int*)alloc((size_t)(N + 1) * 4);
  int* bsum = (int*)alloc(512 * 4);
  int* rank = (int*)alloc((size_t)E * 4);
  int* ssrc = (int*)alloc((size_t)E * 4);
  unsigned* preb = (unsigned*)alloc((size_t)N * 64 * 4);
  float* bnpart = (float*)alloc(64 * 256 * 4);
  float* sc = (float*)alloc(128 * 4);
  float* sh = (float*)alloc(128 * 4);
  unsigned short* Bext = (unsigned short*)alloc(9 * 4 * 64 * 8 * 2);
  (void)n_in; (void)out_size; (void)ws_size;

  // cnt8 (8 private count copies, 3.2 MB) aliases preb: dead before k_agg writes preb.
  int* cnt8 = (int*)preb;

  // edge-region shift: smallest esh with ceil(E/2^esh) <= 8
  int esh = 10;
  while (((E + (1 << esh) - 1) >> esh) > 8) ++esh;

  hipMemsetAsync(cnt8, 0, (size_t)N * 8 * 4, stream);
  hipMemsetAsync(bnpart, 0, 64 * 256 * 4, stream);

  k_prep<<<9, 256, 0, stream>>>(W, att_src, att_dst, Bext);

  int ntiles = (N + 63) / 64;
  k_gemm_count<<<GEMM_BLOCKS + COUNT_BLOCKS, 256, 0, stream>>>(
      x, Bext, hb, a_s, a_d, N, ntiles, ei, cnt8, rank, E, esh);

  int nb = (N + 255) / 256;
  k_scan1<<<nb, 256, 0, stream>>>(cnt8, cnt, incl, bsum, N);
  k_scan2<<<1, 512, 0, stream>>>(bsum, nb);
  k_scan3<<<nb, 256, 0, stream>>>(cnt, incl, bsum, offs, N, E);

  int rsize = (N + 7) / 8;
  k_scatter_rank<<<2048, 256, 0, stream>>>(ei, offs, cnt8, rank, ssrc, E, rsize, esh, N);

  k_agg<<<(N + 3) / 4, 256, 0, stream>>>(hb, a_s, a_d, offs, ssrc, bias, preb, bnpart, N);

  k_bnfinal<<<1, 128, 0, stream>>>(bnpart, gamma, beta, sc, sh, N);

  int npair2 = N * 32;
  k_bnapply<<<(npair2 + 255) / 256, 256, 0, stream>>>(preb, out, sc, sh, npair2);
}

// Round 16
// 219.698 us; speedup vs baseline: 1.2077x; 1.0650x over previous
//
#include <hip/hip_runtime.h>

#define NEG 0.2f
#define MAXD 128
#define GEMM_BLOCKS 1024
#define COUNT_BLOCKS 2048

__device__ __forceinline__ float lrelu(float v) { return v > 0.f ? v : NEG * v; }

// round-to-nearest-even fp32 -> bf16 (returns low 16 bits)
__device__ __forceinline__ unsigned f2bf(float f) {
  unsigned u = __float_as_uint(f);
  u = (u + 0x7FFFu + ((u >> 16) & 1u)) >> 16;
  return u;
}
__device__ __forceinline__ float bf_lo(unsigned u) { return __uint_as_float(u << 16); }
__device__ __forceinline__ float bf_hi(unsigned u) { return __uint_as_float(u & 0xFFFF0000u); }

typedef __attribute__((ext_vector_type(8))) short bf16x8;
typedef __attribute__((ext_vector_type(4))) float f32x4;

// ---- Kernel 0: build Bext (bf16, frag order) + zero cnt8 + zero bnpart (absorbs memsets) ----
__global__ __launch_bounds__(256) void k_prep(const float* __restrict__ W,
                                              const float* __restrict__ att_src,
                                              const float* __restrict__ att_dst,
                                              unsigned short* __restrict__ Bext,
                                              int* __restrict__ cnt8, float* __restrict__ bnpart,
                                              int N) {
  const int gtid = blockIdx.x * 256 + threadIdx.x;
  const int gstride = gridDim.x * 256;
  for (int id = gtid; id < 9 * 4 * 64 * 8; id += gstride) {
    int j = id & 7, lane = (id >> 3) & 63, kb = (id >> 9) & 3, ct = id >> 11;
    int k = kb * 32 + (lane >> 4) * 8 + j;
    int c = ct * 16 + (lane & 15);
    float v;
    if (c < 128) {
      v = W[k * 128 + c];
    } else {
      int slot = c - 128;
      int hd = slot & 3;
      const float* att = (slot < 4) ? att_src : att_dst;
      float s = 0.f;
      for (int jj = 0; jj < 32; ++jj) s = fmaf(W[k * 128 + hd * 32 + jj], att[hd * 32 + jj], s);
      v = s;
    }
    Bext[id] = (unsigned short)f2bf(v);
  }
  for (int i = gtid; i < N * 8; i += gstride) cnt8[i] = 0;
  for (int i = gtid; i < 64 * 256; i += gstride) bnpart[i] = 0.f;
}

// ---- Fused kernel, chunk-interleaved roles (8-block chunks keep &7 XCD pinning) ----
__global__ __launch_bounds__(256) void k_gemm_count(
    const float* __restrict__ x, const unsigned short* __restrict__ Bext,
    unsigned* __restrict__ hb, float* __restrict__ a_s, float* __restrict__ a_d,
    int N, int ntiles,
    const int* __restrict__ ei, int* __restrict__ cnt8, int* __restrict__ rank,
    int E, int esh)
{
  const int tid = threadIdx.x;
  const int chunk = blockIdx.x >> 3;
  if (chunk % 3 == 0) {
    // ================= GEMM path =================
    const int vb = (chunk / 3) * 8 + (blockIdx.x & 7);   // [0,1024)
    const bf16x8* Bfrag = reinterpret_cast<const bf16x8*>(Bext);
    const int w = tid >> 6, lane = tid & 63;
    const int r16 = lane & 15, g = lane >> 4;
    for (int tile = vb; tile < ntiles; tile += GEMM_BLOCKS) {
      int n0 = tile * 64 + w * 16;
      int rowc = min(n0 + r16, N - 1);
      const float* xp = x + (size_t)rowc * 128 + g * 8;
      bf16x8 afr[4];
#pragma unroll
      for (int kb = 0; kb < 4; ++kb) {
        float4 lo = *reinterpret_cast<const float4*>(xp + kb * 32);
        float4 hi = *reinterpret_cast<const float4*>(xp + kb * 32 + 4);
        bf16x8 t;
        t[0] = (short)f2bf(lo.x); t[1] = (short)f2bf(lo.y);
        t[2] = (short)f2bf(lo.z); t[3] = (short)f2bf(lo.w);
        t[4] = (short)f2bf(hi.x); t[5] = (short)f2bf(hi.y);
        t[6] = (short)f2bf(hi.z); t[7] = (short)f2bf(hi.w);
        afr[kb] = t;
      }
#pragma unroll
      for (int ct = 0; ct < 9; ++ct) {
        f32x4 acc = {0.f, 0.f, 0.f, 0.f};
#pragma unroll
        for (int kb = 0; kb < 4; ++kb) {
          bf16x8 bfr = Bfrag[(ct * 4 + kb) * 64 + lane];
          acc = __builtin_amdgcn_mfma_f32_16x16x32_bf16(afr[kb], bfr, acc, 0, 0, 0);
        }
        if (ct < 8) {
#pragma unroll
          for (int r = 0; r < 4; ++r) {
            int orow = n0 + g * 4 + r;
            unsigned b = f2bf(acc[r]);
            unsigned partner = __shfl_xor(b, 1);
            if (((lane & 1) == 0) && orow < N)
              hb[((size_t)orow << 6) + ct * 8 + (r16 >> 1)] = b | (partner << 16);
          }
        } else {
#pragma unroll
          for (int r = 0; r < 4; ++r) {
            int orow = n0 + g * 4 + r;
            if (r16 < 8 && orow < N) {
              if (r16 < 4) a_s[orow * 4 + r16] = acc[r];
              else         a_d[orow * 4 + (r16 - 4)] = acc[r];
            }
          }
        }
      }
    }
  } else {
    // ================= count+rank path (edge-partitioned, XCD-private cnt8) =====
    const int r = blockIdx.x & 7;
    const int cidx = chunk - 1 - (chunk / 3);            // [0,256)
    const int qper = 1 << (esh - 2);                     // quads per region
    const int ebase = r << esh;
    int* cpriv = cnt8 + (size_t)r * N;
    for (int ql = cidx * 256 + tid; ql < qper; ql += 256 * 256) {
      int e0 = ebase + (ql << 2);
      if (e0 >= E) break;
      if (e0 + 3 < E) {
        int4 d = *reinterpret_cast<const int4*>(ei + E + e0);
        int4 rk;
        rk.x = atomicAdd(&cpriv[d.x], 1);
        rk.y = atomicAdd(&cpriv[d.y], 1);
        rk.z = atomicAdd(&cpriv[d.z], 1);
        rk.w = atomicAdd(&cpriv[d.w], 1);
        *reinterpret_cast<int4*>(rank + e0) = rk;
      } else {
        for (int e = e0; e < E; ++e) {
          int d = ei[E + e];
          rank[e] = atomicAdd(&cpriv[d], 1);
        }
      }
    }
  }
}

// ---- Scan 1: per-node 8-way prefix over cnt8 (sub-offsets in place) + block scan ----
// excl[i] = within-block exclusive prefix of node totals; bsum[b] = block total.
__global__ __launch_bounds__(256) void k_scan1(int* __restrict__ cnt8, int* __restrict__ excl,
                                               int* __restrict__ bsum, int N) {
  __shared__ int sm[256];
  int i = blockIdx.x * 256 + threadIdx.x;
  int tot = 0;
  if (i < N) {
    int run = 0;
#pragma unroll
    for (int r = 0; r < 8; ++r) {
      int t = cnt8[(size_t)r * N + i];
      cnt8[(size_t)r * N + i] = run;   // exclusive prefix = per-region sub-offset
      run += t;
    }
    tot = run;
  }
  sm[threadIdx.x] = tot;
  __syncthreads();
  for (int off = 1; off < 256; off <<= 1) {
    int t = (threadIdx.x >= off) ? sm[threadIdx.x - off] : 0;
    __syncthreads();
    sm[threadIdx.x] += t;
    __syncthreads();
  }
  if (i < N) excl[i] = sm[threadIdx.x] - tot;
  if (threadIdx.x == 255) bsum[blockIdx.x] = sm[255];
}

// ---- Scan 2+3 merged: block base from bsum reduce; offs[i]; fold offs into cnt8 slots ----
__global__ __launch_bounds__(256) void k_scan23(const int* __restrict__ excl,
                                                const int* __restrict__ bsum,
                                                int* __restrict__ offs, int* __restrict__ cnt8,
                                                int N, int E) {
  __shared__ int red[256];
  const int b = blockIdx.x;
  int partial = 0;
  for (int j = threadIdx.x; j < b; j += 256) partial += bsum[j];
  red[threadIdx.x] = partial;
  __syncthreads();
  for (int off = 128; off >= 1; off >>= 1) {
    if (threadIdx.x < off) red[threadIdx.x] += red[threadIdx.x + off];
    __syncthreads();
  }
  const int base = red[0];
  int i = b * 256 + threadIdx.x;
  if (i < N) {
    int o = base + excl[i];
    offs[i] = o;
#pragma unroll
    for (int r = 0; r < 8; ++r) cnt8[(size_t)r * N + i] += o;   // full sub-offset
  }
  if (b == 0 && threadIdx.x == 0) offs[N] = E;
}

// ---- XCD-pinned (by dst) ATOMIC-FREE scatter: pos = cnt8[e>>esh][d] + rank[e] ----
__global__ __launch_bounds__(256) void k_scatter_rank(const int* __restrict__ ei,
                                                      const int* __restrict__ cnt8,
                                                      const int* __restrict__ rank,
                                                      int* __restrict__ ssrc, int E, int rsize,
                                                      int esh, int N) {
  const int r = blockIdx.x & 7;
  const int lo = r * rsize, hi = lo + rsize;
  const int gtid = (blockIdx.x >> 3) * 256 + threadIdx.x;
  const int gstride = (gridDim.x >> 3) * 256;
  const int nquad = E >> 2;
  const int4* dst4 = reinterpret_cast<const int4*>(ei + E);
  const int4* rank4 = reinterpret_cast<const int4*>(rank);
  for (int q = gtid; q < nquad; q += gstride) {
    int4 d = dst4[q];
    int e0 = q << 2;
    const int* sub = cnt8 + (size_t)(e0 >> esh) * N;   // quads never straddle regions
    int4 rk = rank4[q];
    if (d.x >= lo && d.x < hi) ssrc[sub[d.x] + rk.x] = ei[e0];
    if (d.y >= lo && d.y < hi) ssrc[sub[d.y] + rk.y] = ei[e0 + 1];
    if (d.z >= lo && d.z < hi) ssrc[sub[d.z] + rk.z] = ei[e0 + 2];
    if (d.w >= lo && d.w < hi) ssrc[sub[d.w] + rk.w] = ei[e0 + 3];
  }
  for (int e = (nquad << 2) + gtid; e < E; e += gstride) {
    int d = ei[E + e];
    if (d >= lo && d < hi) ssrc[cnt8[(size_t)(e >> esh) * N + d] + rank[e]] = ei[e];
  }
}

// ---- k_agg: per-node softmax + aggregation + bias + ELU + fused BN partials ----
__global__ __launch_bounds__(256) void k_agg(
    const unsigned* __restrict__ hb, const float* __restrict__ a_s, const float* __restrict__ a_d,
    const int* __restrict__ offs, const int* __restrict__ ssrc,
    const float* __restrict__ bias, unsigned* __restrict__ preb,
    float* __restrict__ bnpart, int N)
{
  __shared__ float al[4][MAXD][4];
  __shared__ int   ls[4][MAXD];
  __shared__ float sv[4][128];
  const int wv = threadIdx.x >> 6;
  const int lane = threadIdx.x & 63;
  const int n = blockIdx.x * 4 + wv;

  if (n < N) {
    const int hsel = lane >> 4;
    const int start = offs[n], end = offs[n + 1];
    const int deg = end - start;
    const int jm = deg < MAXD ? deg : MAXD;
    float4 adv = *reinterpret_cast<const float4*>(&a_d[n * 4]);
    float4 asv = *reinterpret_cast<const float4*>(&a_s[n * 4]);
    float e0 = __expf(lrelu(asv.x + adv.x));
    float e1 = __expf(lrelu(asv.y + adv.y));
    float e2 = __expf(lrelu(asv.z + adv.z));
    float e3 = __expf(lrelu(asv.w + adv.w));
    float p0 = 0.f, p1 = 0.f, p2 = 0.f, p3 = 0.f;
    for (int j = lane; j < deg; j += 64) {
      int s = ssrc[start + j];
      float4 av = *reinterpret_cast<const float4*>(&a_s[s * 4]);
      float x0 = __expf(lrelu(av.x + adv.x));
      float x1 = __expf(lrelu(av.y + adv.y));
      float x2 = __expf(lrelu(av.z + adv.z));
      float x3 = __expf(lrelu(av.w + adv.w));
      p0 += x0; p1 += x1; p2 += x2; p3 += x3;
      if (j < MAXD) {
        float4 t = make_float4(x0, x1, x2, x3);
        *reinterpret_cast<float4*>(&al[wv][j][0]) = t;
        ls[wv][j] = s;
      }
    }
#pragma unroll
    for (int off = 32; off >= 1; off >>= 1) {
      p0 += __shfl_xor(p0, off);
      p1 += __shfl_xor(p1, off);
      p2 += __shfl_xor(p2, off);
      p3 += __shfl_xor(p3, off);
    }
    float rden0 = 1.f / (p0 + e0), rden1 = 1.f / (p1 + e1);
    float rden2 = 1.f / (p2 + e2), rden3 = 1.f / (p3 + e3);
    for (int j = lane; j < jm; j += 64) {
      float4 t = *reinterpret_cast<float4*>(&al[wv][j][0]);
      t.x *= rden0; t.y *= rden1; t.z *= rden2; t.w *= rden3;
      *reinterpret_cast<float4*>(&al[wv][j][0]) = t;
    }
    float ad_c = (hsel < 2) ? (hsel == 0 ? adv.x : adv.y) : (hsel == 2 ? adv.z : adv.w);
    float rden = (hsel < 2) ? (hsel == 0 ? rden0 : rden1) : (hsel == 2 ? rden2 : rden3);
    float esf = (hsel < 2) ? (hsel == 0 ? e0 : e1) : (hsel == 2 ? e2 : e3);
    unsigned us = hb[((unsigned)n << 6) + lane];
    float wself = esf * rden;
    float acc0 = wself * bf_lo(us);
    float acc1 = wself * bf_hi(us);
    int j = 0;
    for (; j + 8 <= jm; j += 8) {
      int4 sA = *reinterpret_cast<int4*>(&ls[wv][j]);
      int4 sB = *reinterpret_cast<int4*>(&ls[wv][j + 4]);
      unsigned u0 = hb[((unsigned)sA.x << 6) + lane];
      unsigned u1 = hb[((unsigned)sA.y << 6) + lane];
      unsigned u2 = hb[((unsigned)sA.z << 6) + lane];
      unsigned u3 = hb[((unsigned)sA.w << 6) + lane];
      unsigned u4 = hb[((unsigned)sB.x << 6) + lane];
      unsigned u5 = hb[((unsigned)sB.y << 6) + lane];
      unsigned u6 = hb[((unsigned)sB.z << 6) + lane];
      unsigned u7 = hb[((unsigned)sB.w << 6) + lane];
      float w0 = al[wv][j][hsel];
      float w1 = al[wv][j + 1][hsel];
      float w2 = al[wv][j + 2][hsel];
      float w3 = al[wv][j + 3][hsel];
      float w4 = al[wv][j + 4][hsel];
      float w5 = al[wv][j + 5][hsel];
      float w6 = al[wv][j + 6][hsel];
      float w7 = al[wv][j + 7][hsel];
      acc0 = fmaf(w0, bf_lo(u0), acc0);
      acc1 = fmaf(w0, bf_hi(u0), acc1);
      acc0 = fmaf(w1, bf_lo(u1), acc0);
      acc1 = fmaf(w1, bf_hi(u1), acc1);
      acc0 = fmaf(w2, bf_lo(u2), acc0);
      acc1 = fmaf(w2, bf_hi(u2), acc1);
      acc0 = fmaf(w3, bf_lo(u3), acc0);
      acc1 = fmaf(w3, bf_hi(u3), acc1);
      acc0 = fmaf(w4, bf_lo(u4), acc0);
      acc1 = fmaf(w4, bf_hi(u4), acc1);
      acc0 = fmaf(w5, bf_lo(u5), acc0);
      acc1 = fmaf(w5, bf_hi(u5), acc1);
      acc0 = fmaf(w6, bf_lo(u6), acc0);
      acc1 = fmaf(w6, bf_hi(u6), acc1);
      acc0 = fmaf(w7, bf_lo(u7), acc0);
      acc1 = fmaf(w7, bf_hi(u7), acc1);
    }
    for (; j + 4 <= jm; j += 4) {
      int4 s4 = *reinterpret_cast<int4*>(&ls[wv][j]);
      unsigned u0 = hb[((unsigned)s4.x << 6) + lane];
      unsigned u1 = hb[((unsigned)s4.y << 6) + lane];
      unsigned u2 = hb[((unsigned)s4.z << 6) + lane];
      unsigned u3 = hb[((unsigned)s4.w << 6) + lane];
      float w0 = al[wv][j][hsel];
      float w1 = al[wv][j + 1][hsel];
      float w2 = al[wv][j + 2][hsel];
      float w3 = al[wv][j + 3][hsel];
      acc0 = fmaf(w0, bf_lo(u0), acc0);
      acc1 = fmaf(w0, bf_hi(u0), acc1);
      acc0 = fmaf(w1, bf_lo(u1), acc0);
      acc1 = fmaf(w1, bf_hi(u1), acc1);
      acc0 = fmaf(w2, bf_lo(u2), acc0);
      acc1 = fmaf(w2, bf_hi(u2), acc1);
      acc0 = fmaf(w3, bf_lo(u3), acc0);
      acc1 = fmaf(w3, bf_hi(u3), acc1);
    }
    for (; j < jm; ++j) {
      int s = ls[wv][j];
      float w = al[wv][j][hsel];
      unsigned u = hb[((unsigned)s << 6) + lane];
      acc0 = fmaf(w, bf_lo(u), acc0);
      acc1 = fmaf(w, bf_hi(u), acc1);
    }
    for (int jj = MAXD; jj < deg; ++jj) {
      int s = ssrc[start + jj];
      float q = a_s[s * 4 + hsel];
      unsigned u = hb[((unsigned)s << 6) + lane];
      float w = __expf(lrelu(q + ad_c)) * rden;
      acc0 = fmaf(w, bf_lo(u), acc0);
      acc1 = fmaf(w, bf_hi(u), acc1);
    }
    float2 bv = *reinterpret_cast<const float2*>(&bias[2 * lane]);
    float o0 = acc0 + bv.x;
    float o1 = acc1 + bv.y;
    o0 = o0 > 0.f ? o0 : expm1f(o0);
    o1 = o1 > 0.f ? o1 : expm1f(o1);
    preb[((size_t)n << 6) + lane] = f2bf(o0) | (f2bf(o1) << 16);
    sv[wv][2 * lane] = o0;
    sv[wv][2 * lane + 1] = o1;
  } else {
    sv[wv][2 * lane] = 0.f;
    sv[wv][2 * lane + 1] = 0.f;
  }
  __syncthreads();
  int t = threadIdx.x;
  if (t < 128) {
    float s = 0.f, q = 0.f;
#pragma unroll
    for (int w2 = 0; w2 < 4; ++w2) {
      float v = sv[w2][t];
      s += v;
      q = fmaf(v, v, q);
    }
    float* slot = bnpart + (size_t)(blockIdx.x & 63) * 256;
    atomicAdd(&slot[t], s);
    atomicAdd(&slot[128 + t], q);
  }
}

// ---- BN scale/shift from partials ----
__global__ void k_bnfinal(const float* __restrict__ bnpart,
                          const float* __restrict__ gamma, const float* __restrict__ beta,
                          float* __restrict__ sc, float* __restrict__ sh, int N) {
  int c = threadIdx.x;
  float s = 0.f, q = 0.f;
  for (int p = 0; p < 64; ++p) {
    s += bnpart[p * 256 + c];
    q += bnpart[p * 256 + 128 + c];
  }
  float invn = 1.f / (float)N;
  float mean = s * invn;
  float var = q * invn - mean * mean;
  float scl = gamma[c] * rsqrtf(var + 1e-5f);
  sc[c] = scl;
  sh[c] = beta[c] - mean * scl;
}

// ---- apply BN: read packed bf16 pre, write fp32 out ----
__global__ __launch_bounds__(256) void k_bnapply(const unsigned* __restrict__ preb,
                                                 float* __restrict__ out,
                                                 const float* __restrict__ sc,
                                                 const float* __restrict__ sh, int npair2) {
  int i = blockIdx.x * blockDim.x + threadIdx.x;
  if (i >= npair2) return;
  uint2 u = reinterpret_cast<const uint2*>(preb)[i];
  int p0 = i * 2;
  int c0 = (p0 & 63) * 2;
  float4 scv = *reinterpret_cast<const float4*>(&sc[c0]);
  float4 shv = *reinterpret_cast<const float4*>(&sh[c0]);
  float4 v;
  v.x = fmaf(bf_lo(u.x), scv.x, shv.x);
  v.y = fmaf(bf_hi(u.x), scv.y, shv.y);
  v.z = fmaf(bf_lo(u.y), scv.z, shv.z);
  v.w = fmaf(bf_hi(u.y), scv.w, shv.w);
  reinterpret_cast<float4*>(out)[i] = v;
}

extern "C" void kernel_launch(void* const* d_in, const int* in_sizes, int n_in,
                              void* d_out, int out_size, void* d_ws, size_t ws_size,
                              hipStream_t stream) {
  const float* x = (const float*)d_in[0];
  const int* ei = (const int*)d_in[1];
  const float* W = (const float*)d_in[2];
  const float* att_src = (const float*)d_in[3];
  const float* att_dst = (const float*)d_in[4];
  const float* bias = (const float*)d_in[5];
  const float* gamma = (const float*)d_in[6];
  const float* beta = (const float*)d_in[7];
  float* out = (float*)d_out;

  const int N = in_sizes[0] / 128;
  const int E = in_sizes[1] / 2;

  char* ws = (char*)d_ws;
  size_t off = 0;
  auto alloc = [&](size_t bytes) {
    void* p = ws + off;
    off = (off + bytes + 255) & ~(size_t)255;
    return p;
  };
  unsigned* hb = (unsigned*)alloc((size_t)N * 64 * 4);
  float* a_s = (float*)alloc((size_t)N * 4 * 4);
  float* a_d = (float*)alloc((size_t)N * 4 * 4);
  int* excl = (int*)alloc((size_t)N * 4);
  int* offs = (int*)alloc((size_t)(N + 1) * 4);
  int* bsum = (int*)alloc(512 * 4);
  int* rank = (int*)alloc((size_t)E * 4);
  int* ssrc = (int*)alloc((size_t)E * 4);
  unsigned* preb = (unsigned*)alloc((size_t)N * 64 * 4);
  float* bnpart = (float*)alloc(64 * 256 * 4);
  float* sc = (float*)alloc(128 * 4);
  float* sh = (float*)alloc(128 * 4);
  unsigned short* Bext = (unsigned short*)alloc(9 * 4 * 64 * 8 * 2);
  (void)n_in; (void)out_size; (void)ws_size;

  // cnt8 (8 private count copies, 3.2 MB) aliases preb: dead before k_agg writes preb.
  int* cnt8 = (int*)preb;

  // edge-region shift: smallest esh with ceil(E/2^esh) <= 8
  int esh = 10;
  while (((E + (1 << esh) - 1) >> esh) > 8) ++esh;

  // k_prep builds Bext AND zeroes cnt8 + bnpart (replaces two memsets)
  k_prep<<<64, 256, 0, stream>>>(W, att_src, att_dst, Bext, cnt8, bnpart, N);

  int ntiles = (N + 63) / 64;
  k_gemm_count<<<GEMM_BLOCKS + COUNT_BLOCKS, 256, 0, stream>>>(
      x, Bext, hb, a_s, a_d, N, ntiles, ei, cnt8, rank, E, esh);

  int nb = (N + 255) / 256;
  k_scan1<<<nb, 256, 0, stream>>>(cnt8, excl, bsum, N);
  k_scan23<<<nb, 256, 0, stream>>>(excl, bsum, offs, cnt8, N, E);

  int rsize = (N + 7) / 8;
  k_scatter_rank<<<2048, 256, 0, stream>>>(ei, cnt8, rank, ssrc, E, rsize, esh, N);

  k_agg<<<(N + 3) / 4, 256, 0, stream>>>(hb, a_s, a_d, offs, ssrc, bias, preb, bnpart, N);

  k_bnfinal<<<1, 128, 0, stream>>>(bnpart, gamma, beta, sc, sh, N);

  int npair2 = N * 32;
  k_bnapply<<<(npair2 + 255) / 256, 256, 0, stream>>>(preb, out, sc, sh, npair2);
}